// Round 10
// baseline (100.146 us; speedup 1.0000x reference)
//
#include <hip/hip_runtime.h>

// Problem constants (fixed by setup_inputs)
#define NB 16
#define NC 64
#define TX 128
#define TY 128
#define DD 768
#define BK 64
#define NT (DD / BK) // 12 K-steps

typedef __bf16 bf16_t;
typedef __bf16 bf16x8 __attribute__((ext_vector_type(8)));
typedef __bf16 bf16x4 __attribute__((ext_vector_type(4)));
typedef float  f32x4  __attribute__((ext_vector_type(4)));

// LDS rows are 128 B (64 bf16). XOR swizzle: 16B slot ^= row&7 -> frag b128
// reads (16 lanes, same slot, rows r..r+15) spread over 8 slots, ~2-way free.
__device__ __forceinline__ unsigned swz(unsigned r, unsigned byte) {
  return r * 128u + ((((byte >> 4) & 7u) ^ (r & 7u)) << 4) + (byte & 15u);
}

// fp32x4 -> bf16x4 (packs to v_cvt_pk_bf16_f32), 8B store
__device__ __forceinline__ void cvt_store(void* dst, f32x4 v) {
  bf16x4 q;
  q[0] = (bf16_t)v[0]; q[1] = (bf16_t)v[1]; q[2] = (bf16_t)v[2]; q[3] = (bf16_t)v[3];
  *(bf16x4*)dst = q;
}

// ===================== y-split main kernel =====================
// Each block: (b, c, y-half h). A = xs[b] full 128 x-rows; B = 64 y-rows.
// LDS 48 KB/block -> 3 blocks/CU, 24 waves/CU (vs 16 before): +50% foreign
// work per CU to hide HBM jitter at the per-iter barrier. Live VGPR ~78.
// Output: partial max over this y-half, per x (128 floats) -> ws.
__global__ __launch_bounds__(512, 3) void ur_half_kernel(
    const float* __restrict__ xs, const float* __restrict__ ys,
    float* __restrict__ pmax)
{
  __shared__ char ldsA[2][16384];  // [buf][128 rows * 128 B]
  __shared__ char ldsB[2][8192];   // [buf][ 64 rows * 128 B]

  // u%16 == b -> all same-b blocks on one XCD; xs[b] L2-resident there.
  const int u  = blockIdx.x;       // 0..2047
  const int b  = u & 15;
  const int h  = (u >> 4) & 1;
  const int c  = u >> 5;
  const int bc = b * NC + c;

  const int tid  = threadIdx.x;
  const int lane = tid & 63;
  const int w    = tid >> 6;       // wave 0..7

  // Staging: A 2048 f32x4/tile -> 4 chunks/thread (rows r0+32i, i=0..3);
  //          B 1024 f32x4/tile -> 2 chunks/thread (rows r0+32i, i=0,1).
  // (row&7) i-invariant -> LDS offset = soff + 4096*i for both.
  const unsigned r0 = (unsigned)tid >> 4;   // 0..31
  const unsigned j0 = (unsigned)tid & 15u;  // 0..15
  const unsigned soff = swz(r0, j0 * 8u);
  const float* Ap = xs + (size_t)b  * TX * DD + r0 * DD + j0 * 4;
  const float* Bp = ys + (size_t)bc * TY * DD + (size_t)(h * 64 + r0) * DD + j0 * 4;

  f32x4 acc[4];
  #pragma unroll
  for (int n = 0; n < 4; ++n)
    #pragma unroll
    for (int k = 0; k < 4; ++k)
      acc[n][k] = 0.0f;

  f32x4 pa[4], pb[2];

  // ---- prologue: tile0 -> regs -> lds[0]; tile1 -> regs ----
  #pragma unroll
  for (int i = 0; i < 4; ++i)
    pa[i] = *(const f32x4*)(Ap + i * 32 * DD);
  #pragma unroll
  for (int i = 0; i < 2; ++i)
    pb[i] = __builtin_nontemporal_load((const f32x4*)(Bp + i * 32 * DD));
  #pragma unroll
  for (int i = 0; i < 4; ++i)
    cvt_store(&ldsA[0][soff + 4096u * i], pa[i]);
  #pragma unroll
  for (int i = 0; i < 2; ++i)
    cvt_store(&ldsB[0][soff + 4096u * i], pb[i]);
  #pragma unroll
  for (int i = 0; i < 4; ++i)
    pa[i] = *(const f32x4*)(Ap + BK + i * 32 * DD);
  #pragma unroll
  for (int i = 0; i < 2; ++i)
    pb[i] = __builtin_nontemporal_load((const f32x4*)(Bp + BK + i * 32 * DD));
  // barrier WITHOUT vmem drain: only LDS ops must be visible
  asm volatile("s_waitcnt lgkmcnt(0)" ::: "memory");
  __builtin_amdgcn_s_barrier();
  asm volatile("" ::: "memory");

  const unsigned kb = ((unsigned)lane >> 4) << 4;          // 0/16/32/48 B
  const unsigned rA = (unsigned)(w * 16 + (lane & 15));    // A row this wave
  const unsigned rB = (unsigned)(lane & 15);               // B rows (y)
  const unsigned aoff0 = swz(rA, kb), aoff1 = swz(rA, 64u + kb);
  const unsigned boff0 = swz(rB, kb), boff1 = swz(rB, 64u + kb); // +16 rows=+2048

  int cur = 0;
  for (int t = 0; t < NT; ++t) {
    // 1) convert + write tile t+1 (its loads got a full iteration in flight)
    if (t + 1 < NT) {
      #pragma unroll
      for (int i = 0; i < 4; ++i)
        cvt_store(&ldsA[cur ^ 1][soff + 4096u * i], pa[i]);
      #pragma unroll
      for (int i = 0; i < 2; ++i)
        cvt_store(&ldsB[cur ^ 1][soff + 4096u * i], pb[i]);
    }
    // 2) issue tile t+2 loads; they stay in flight across the raw barrier
    if (t + 2 < NT) {
      #pragma unroll
      for (int i = 0; i < 4; ++i)
        pa[i] = *(const f32x4*)(Ap + (t + 2) * BK + i * 32 * DD);
      #pragma unroll
      for (int i = 0; i < 2; ++i)
        pb[i] = __builtin_nontemporal_load((const f32x4*)(Bp + (t + 2) * BK + i * 32 * DD));
    }
    // 3) fragments + MFMA, two K=32 substeps, 4 n-frags each
    {
      bf16x8 af = *(const bf16x8*)&ldsA[cur][aoff0];
      bf16x8 bfr[4];
      #pragma unroll
      for (int n = 0; n < 4; ++n)
        bfr[n] = *(const bf16x8*)&ldsB[cur][boff0 + 2048u * n];
      #pragma unroll
      for (int n = 0; n < 4; ++n)
        acc[n] = __builtin_amdgcn_mfma_f32_16x16x32_bf16(af, bfr[n], acc[n], 0, 0, 0);
    }
    {
      bf16x8 af = *(const bf16x8*)&ldsA[cur][aoff1];
      bf16x8 bfr[4];
      #pragma unroll
      for (int n = 0; n < 4; ++n)
        bfr[n] = *(const bf16x8*)&ldsB[cur][boff1 + 2048u * n];
      #pragma unroll
      for (int n = 0; n < 4; ++n)
        acc[n] = __builtin_amdgcn_mfma_f32_16x16x32_bf16(af, bfr[n], acc[n], 0, 0, 0);
    }
    // barrier with LDS-only drain (vmem prefetch stays in flight)
    asm volatile("s_waitcnt lgkmcnt(0)" ::: "memory");
    __builtin_amdgcn_s_barrier();
    asm volatile("" ::: "memory");
    cur ^= 1;
  }

  // ---- partial reduction: max over this y-half ----
  // acc element (n,i) at lane l: x = w*16 + (l>>4)*4 + i, y = n*16 + (l&15)
  float rm[4];
  #pragma unroll
  for (int i = 0; i < 4; ++i)
    rm[i] = fmaxf(fmaxf(acc[0][i], acc[1][i]), fmaxf(acc[2][i], acc[3][i]));
  #pragma unroll
  for (int mask = 1; mask < 16; mask <<= 1)
    #pragma unroll
    for (int i = 0; i < 4; ++i)
      rm[i] = fmaxf(rm[i], __shfl_xor(rm[i], mask, 64));

  // lanes 0,16,32,48 hold the 4 x-groups of this wave: write 128 partials
  if ((lane & 15) == 0) {
    float* p = pmax + ((size_t)(bc * 2 + h)) * 128 + w * 16 + (lane >> 4) * 4;
    #pragma unroll
    for (int i = 0; i < 4; ++i) p[i] = rm[i];
  }
}

// ===================== combine kernel =====================
// out[bc] = sum_x max(p[bc][0][x], p[bc][1][x]); one wave per bc.
__global__ __launch_bounds__(256) void ur_comb_kernel(
    const float* __restrict__ pmax, float* __restrict__ out)
{
  const int gw   = blockIdx.x * 4 + (threadIdx.x >> 6);  // bc 0..1023
  const int lane = threadIdx.x & 63;
  const float* p0 = pmax + (size_t)gw * 256;
  const float* p1 = p0 + 128;
  float v = fmaxf(p0[lane], p1[lane]) + fmaxf(p0[lane + 64], p1[lane + 64]);
  #pragma unroll
  for (int mask = 1; mask < 64; mask <<= 1)
    v += __shfl_xor(v, mask, 64);
  if (lane == 0) out[gw] = v;
}

// ===================== fallback (round-9 best, single kernel) =====================
__global__ __launch_bounds__(512, 2) void ur_score_kernel(
    const float* __restrict__ xs, const float* __restrict__ ys,
    float* __restrict__ out)
{
  __shared__ char lds[2][2][16384];
  __shared__ float wsum[8];

  const int u  = blockIdx.x;
  const int b  = u & 15;
  const int c  = u >> 4;
  const int bc = b * NC + c;

  const int tid  = threadIdx.x;
  const int lane = tid & 63;
  const int w    = tid >> 6;

  const unsigned r0 = (unsigned)tid >> 4;
  const unsigned j0 = (unsigned)tid & 15u;
  const unsigned soff0 = swz(r0, j0 * 8u);
  const float* Ap = xs + (size_t)b  * TX * DD + r0 * DD + j0 * 4;
  const float* Bp = ys + (size_t)bc * TY * DD + r0 * DD + j0 * 4;

  f32x4 acc[8];
  #pragma unroll
  for (int n = 0; n < 8; ++n)
    #pragma unroll
    for (int k = 0; k < 4; ++k)
      acc[n][k] = 0.0f;

  f32x4 pa[4], pb[4];

  #pragma unroll
  for (int i = 0; i < 4; ++i) {
    pa[i] = *(const f32x4*)(Ap + i * 32 * DD);
    pb[i] = __builtin_nontemporal_load((const f32x4*)(Bp + i * 32 * DD));
  }
  #pragma unroll
  for (int i = 0; i < 4; ++i) {
    cvt_store(&lds[0][0][soff0 + 4096u * i], pa[i]);
    cvt_store(&lds[0][1][soff0 + 4096u * i], pb[i]);
  }
  #pragma unroll
  for (int i = 0; i < 4; ++i) {
    pa[i] = *(const f32x4*)(Ap + BK + i * 32 * DD);
    pb[i] = __builtin_nontemporal_load((const f32x4*)(Bp + BK + i * 32 * DD));
  }
  asm volatile("s_waitcnt lgkmcnt(0)" ::: "memory");
  __builtin_amdgcn_s_barrier();
  asm volatile("" ::: "memory");

  const unsigned kb = ((unsigned)lane >> 4) << 4;
  const unsigned rA = (unsigned)(w * 16 + (lane & 15));
  const unsigned rB = (unsigned)(lane & 15);
  const unsigned aoff0 = swz(rA, kb), aoff1 = swz(rA, 64u + kb);
  const unsigned boff0 = swz(rB, kb), boff1 = swz(rB, 64u + kb);

  int cur = 0;
  for (int t = 0; t < NT; ++t) {
    if (t + 1 < NT) {
      #pragma unroll
      for (int i = 0; i < 4; ++i) {
        cvt_store(&lds[cur ^ 1][0][soff0 + 4096u * i], pa[i]);
        cvt_store(&lds[cur ^ 1][1][soff0 + 4096u * i], pb[i]);
      }
    }
    if (t + 2 < NT) {
      #pragma unroll
      for (int i = 0; i < 4; ++i) {
        pa[i] = *(const f32x4*)(Ap + (t + 2) * BK + i * 32 * DD);
        pb[i] = __builtin_nontemporal_load((const f32x4*)(Bp + (t + 2) * BK + i * 32 * DD));
      }
    }
    {
      bf16x8 af0 = *(const bf16x8*)&lds[cur][0][aoff0];
      bf16x8 bfr[8];
      #pragma unroll
      for (int n = 0; n < 8; ++n)
        bfr[n] = *(const bf16x8*)&lds[cur][1][boff0 + 2048u * n];
      #pragma unroll
      for (int n = 0; n < 8; ++n)
        acc[n] = __builtin_amdgcn_mfma_f32_16x16x32_bf16(af0, bfr[n], acc[n], 0, 0, 0);
    }
    {
      bf16x8 af1 = *(const bf16x8*)&lds[cur][0][aoff1];
      bf16x8 bfr[8];
      #pragma unroll
      for (int n = 0; n < 8; ++n)
        bfr[n] = *(const bf16x8*)&lds[cur][1][boff1 + 2048u * n];
      #pragma unroll
      for (int n = 0; n < 8; ++n)
        acc[n] = __builtin_amdgcn_mfma_f32_16x16x32_bf16(af1, bfr[n], acc[n], 0, 0, 0);
    }
    asm volatile("s_waitcnt lgkmcnt(0)" ::: "memory");
    __builtin_amdgcn_s_barrier();
    asm volatile("" ::: "memory");
    cur ^= 1;
  }

  float rm[4];
  #pragma unroll
  for (int i = 0; i < 4; ++i) {
    float v = acc[0][i];
    #pragma unroll
    for (int n = 1; n < 8; ++n) v = fmaxf(v, acc[n][i]);
    rm[i] = v;
  }
  #pragma unroll
  for (int mask = 1; mask < 16; mask <<= 1)
    #pragma unroll
    for (int i = 0; i < 4; ++i)
      rm[i] = fmaxf(rm[i], __shfl_xor(rm[i], mask, 64));

  float ps = rm[0] + rm[1] + rm[2] + rm[3];
  ps += __shfl_xor(ps, 16, 64);
  ps += __shfl_xor(ps, 32, 64);

  if (lane == 0) wsum[w] = ps;
  __syncthreads();
  if (tid == 0) {
    float s = 0.0f;
    #pragma unroll
    for (int i = 0; i < 8; ++i) s += wsum[i];
    out[bc] = s;
  }
}

extern "C" void kernel_launch(void* const* d_in, const int* in_sizes, int n_in,
                              void* d_out, int out_size, void* d_ws, size_t ws_size,
                              hipStream_t stream) {
  const float* xs = (const float*)d_in[0];
  const float* ys = (const float*)d_in[1];
  float* out = (float*)d_out;
  const size_t need = (size_t)NB * NC * 2 * 128 * sizeof(float);  // 1 MB
  if (ws_size >= need) {
    float* pmax = (float*)d_ws;
    ur_half_kernel<<<dim3(NB * NC * 2), dim3(512), 0, stream>>>(xs, ys, pmax);
    ur_comb_kernel<<<dim3(NB * NC / 4), dim3(256), 0, stream>>>(pmax, out);
  } else {
    ur_score_kernel<<<dim3(NB * NC), dim3(512), 0, stream>>>(xs, ys, out);
  }
}

// Round 11
// 75.166 us; speedup vs baseline: 1.3323x; 1.3323x over previous
//
#include <hip/hip_runtime.h>

// Problem constants (fixed by setup_inputs)
#define NB 16
#define NC 64
#define TX 128
#define TY 128
#define DD 768
#define BK 64
#define NT (DD / BK) // 12 K-steps

typedef __bf16 bf16_t;
typedef __bf16 bf16x8 __attribute__((ext_vector_type(8)));
typedef __bf16 bf16x4 __attribute__((ext_vector_type(4)));
typedef float  f32x4  __attribute__((ext_vector_type(4)));

// LDS tile: 128 rows x 64 bf16 = 128 B/row. XOR swizzle: 16B slot ^= row&7.
// Frag b128 reads (16 lanes, same slot, rows r..r+15) spread across 8 slots
// -> ~2-way, free (m136); writes ~4-way.
__device__ __forceinline__ unsigned swz(unsigned r, unsigned byte) {
  return r * 128u + ((((byte >> 4) & 7u) ^ (r & 7u)) << 4) + (byte & 15u);
}

// fp32x4 -> bf16x4 (packs to v_cvt_pk_bf16_f32), 8B store
__device__ __forceinline__ void cvt_store(void* dst, f32x4 v) {
  bf16x4 q;
  q[0] = (bf16_t)v[0]; q[1] = (bf16_t)v[1]; q[2] = (bf16_t)v[2]; q[3] = (bf16_t)v[3];
  *(bf16x4*)dst = q;
}

// 8 waves x 64 = 512 threads; each wave owns a 16x128 output strip.
// 2 blocks/CU (128 KB LDS), 16 waves/CU, <=128 VGPR. Best-measured
// structure (75.1 us): BK=64 double-buffer, store-late T14 schedule,
// lgkm-only barriers, paired-column B bursts on even iters.
__global__ __launch_bounds__(512, 2) void ur_score_kernel(
    const float* __restrict__ xs, const float* __restrict__ ys,
    float* __restrict__ out)
{
  // [buf][A=0/B=1][128 rows * 128 B] -- 64 KB/block
  __shared__ char lds[2][2][16384];
  __shared__ float wsum[8];

  // XCD-aware remap: u%16 == b -> u%8 == b%8, all same-b blocks on one XCD;
  // xs[b] (393 KB fp32) stays L2-resident there.
  const int u  = blockIdx.x;
  const int b  = u & 15;
  const int c  = u >> 4;
  const int bc = b * NC + c;

  const int tid  = threadIdx.x;
  const int lane = tid & 63;
  const int w    = tid >> 6;         // wave 0..7

  // Staging: 2048 float4/tile per operand, 512 threads -> 4 chunks each at
  //   row = r0 + 32*i (i=0..3). (row&7) i-invariant -> LDS off = soff0+4096i.
  const unsigned r0 = (unsigned)tid >> 4;   // 0..31
  const unsigned j0 = (unsigned)tid & 15u;  // 0..15
  const unsigned soff0 = swz(r0, j0 * 8u);
  const float* Ap = xs + (size_t)b  * TX * DD + r0 * DD + j0 * 4;
  const float* Bp = ys + (size_t)bc * TY * DD + r0 * DD + j0 * 4;

  f32x4 acc[8];
  #pragma unroll
  for (int n = 0; n < 8; ++n)
    #pragma unroll
    for (int k = 0; k < 4; ++k)
      acc[n][k] = 0.0f;

  f32x4 pa[4];          // A prefetch, 1-deep (L2-resident)
  f32x4 pbE[4], pbO[4]; // B prefetch, paired-column burst sets

  // ---- prologue: A(0),B(0),B(1) -> regs; A(0),B(0) -> lds[0]; A(1) -> regs
  #pragma unroll
  for (int i = 0; i < 4; ++i)
    pa[i]  = *(const f32x4*)(Ap + i * 32 * DD);
  #pragma unroll
  for (int i = 0; i < 4; ++i) {   // paired burst: cols 0..511 B, same pages
    pbE[i] = __builtin_nontemporal_load((const f32x4*)(Bp + i * 32 * DD));
    pbO[i] = __builtin_nontemporal_load((const f32x4*)(Bp + BK + i * 32 * DD));
  }
  #pragma unroll
  for (int i = 0; i < 4; ++i) {
    cvt_store(&lds[0][0][soff0 + 4096u * i], pa[i]);
    cvt_store(&lds[0][1][soff0 + 4096u * i], pbE[i]);
  }
  #pragma unroll
  for (int i = 0; i < 4; ++i)
    pa[i]  = *(const f32x4*)(Ap + BK + i * 32 * DD);
  // barrier WITHOUT vmem drain: only LDS ops must be visible
  asm volatile("s_waitcnt lgkmcnt(0)" ::: "memory");
  __builtin_amdgcn_s_barrier();
  asm volatile("" ::: "memory");

  const unsigned kb = ((unsigned)lane >> 4) << 4;          // 0/16/32/48 B
  const unsigned rA = (unsigned)(w * 16 + (lane & 15));    // A row this wave
  const unsigned rB = (unsigned)(lane & 15);               // B rows (y)
  const unsigned aoff0 = swz(rA, kb), aoff1 = swz(rA, 64u + kb);
  const unsigned boff0 = swz(rB, kb), boff1 = swz(rB, 64u + kb); // +16 rows=+2048

  // Even iter T: store A(T+1),B(T+1)=pbO; issue A(T+2); burst pbE=B(T+2),
  //              pbO=B(T+3) back-to-back (column-adjacent -> page hits).
  // Odd  iter T: store A(T+1),B(T+1)=pbE; issue A(T+2); no B issue.
  // MFMA on lds[CUR]; lgkm-only barrier (vmem prefetch stays in flight).
  #define ITER(T, CUR, PBUSE, DOBURST)                                            \
  {                                                                               \
    if ((T) + 1 < NT) {                                                           \
      _Pragma("unroll")                                                           \
      for (int i = 0; i < 4; ++i) {                                               \
        cvt_store(&lds[(CUR) ^ 1][0][soff0 + 4096u * i], pa[i]);                  \
        cvt_store(&lds[(CUR) ^ 1][1][soff0 + 4096u * i], PBUSE[i]);               \
      }                                                                           \
    }                                                                             \
    if ((T) + 2 < NT) {                                                           \
      _Pragma("unroll")                                                           \
      for (int i = 0; i < 4; ++i)                                                 \
        pa[i] = *(const f32x4*)(Ap + ((T) + 2) * BK + i * 32 * DD);               \
    }                                                                             \
    if (DOBURST) {                                                                \
      if ((T) + 3 < NT) {                                                         \
        _Pragma("unroll")                                                         \
        for (int i = 0; i < 4; ++i) {                                             \
          pbE[i] = __builtin_nontemporal_load(                                    \
              (const f32x4*)(Bp + ((T) + 2) * BK + i * 32 * DD));                 \
          pbO[i] = __builtin_nontemporal_load(                                    \
              (const f32x4*)(Bp + ((T) + 3) * BK + i * 32 * DD));                 \
        }                                                                         \
      } else if ((T) + 2 < NT) {                                                  \
        _Pragma("unroll")                                                         \
        for (int i = 0; i < 4; ++i)                                               \
          pbE[i] = __builtin_nontemporal_load(                                    \
              (const f32x4*)(Bp + ((T) + 2) * BK + i * 32 * DD));                 \
      }                                                                           \
    }                                                                             \
    {                                                                             \
      bf16x8 af0 = *(const bf16x8*)&lds[CUR][0][aoff0];                           \
      bf16x8 bfr[8];                                                              \
      _Pragma("unroll")                                                           \
      for (int n = 0; n < 8; ++n)                                                 \
        bfr[n] = *(const bf16x8*)&lds[CUR][1][boff0 + 2048u * n];                 \
      _Pragma("unroll")                                                           \
      for (int n = 0; n < 8; ++n)                                                 \
        acc[n] = __builtin_amdgcn_mfma_f32_16x16x32_bf16(af0, bfr[n], acc[n], 0, 0, 0); \
    }                                                                             \
    {                                                                             \
      bf16x8 af1 = *(const bf16x8*)&lds[CUR][0][aoff1];                           \
      bf16x8 bfr[8];                                                              \
      _Pragma("unroll")                                                           \
      for (int n = 0; n < 8; ++n)                                                 \
        bfr[n] = *(const bf16x8*)&lds[CUR][1][boff1 + 2048u * n];                 \
      _Pragma("unroll")                                                           \
      for (int n = 0; n < 8; ++n)                                                 \
        acc[n] = __builtin_amdgcn_mfma_f32_16x16x32_bf16(af1, bfr[n], acc[n], 0, 0, 0); \
    }                                                                             \
    asm volatile("s_waitcnt lgkmcnt(0)" ::: "memory");                            \
    __builtin_amdgcn_s_barrier();                                                 \
    asm volatile("" ::: "memory");                                                \
  }

  #pragma unroll 1
  for (int tt = 0; tt < NT; tt += 2) {
    ITER(tt,     0, pbO, 1);   // even: store pbO, burst-load pbE+pbO
    ITER(tt + 1, 1, pbE, 0);   // odd:  store pbE, no B issue
  }
  #undef ITER

  // ---- reduction: max over y, sum over x ----
  // acc element (n,i) at lane l: x = w*16 + (l>>4)*4 + i, y = n*16 + (l&15)
  float rm[4];
  #pragma unroll
  for (int i = 0; i < 4; ++i) {
    float v = acc[0][i];
    #pragma unroll
    for (int n = 1; n < 8; ++n) v = fmaxf(v, acc[n][i]);
    rm[i] = v;
  }
  // max across the 16 lanes holding different y for the same x-set
  #pragma unroll
  for (int mask = 1; mask < 16; mask <<= 1)
    #pragma unroll
    for (int i = 0; i < 4; ++i)
      rm[i] = fmaxf(rm[i], __shfl_xor(rm[i], mask, 64));

  // per-lane sum over its 4 distinct x rows, then combine the 4 lane-groups
  float ps = rm[0] + rm[1] + rm[2] + rm[3];
  ps += __shfl_xor(ps, 16, 64);
  ps += __shfl_xor(ps, 32, 64);

  if (lane == 0) wsum[w] = ps;
  __syncthreads();
  if (tid == 0) {
    float s = 0.0f;
    #pragma unroll
    for (int i = 0; i < 8; ++i) s += wsum[i];
    out[bc] = s;
  }
}

extern "C" void kernel_launch(void* const* d_in, const int* in_sizes, int n_in,
                              void* d_out, int out_size, void* d_ws, size_t ws_size,
                              hipStream_t stream) {
  const float* xs = (const float*)d_in[0];
  const float* ys = (const float*)d_in[1];
  float* out = (float*)d_out;
  ur_score_kernel<<<dim3(NB * NC), dim3(512), 0, stream>>>(xs, ys, out);
}